// Round 8
// baseline (286.082 us; speedup 1.0000x reference)
//
#include <hip/hip_runtime.h>
#include <math.h>

// CRF loss: B=256, L=256, T=50.
// R18: merge fwd+bwd into ONE 1024-thread block per batch (grid=256=CUs).
//   R17 (512x512thr blocks) showed only ~1 block/CU resident (Occupancy
//   20.6% ~= 8 waves/CU) -> the grid ran as 2 sequential rounds: 69us.
//   R18 forces co-residency: 16 waves/block = 4 waves/SIMD on one CU.
//   Waves 0-7: fwd segments (R14/R16-verified STEPF right-mult).
//   Waves 8-15: bwd segments (R16-verified STEPB left-mult).
//   Per-wave work identical to R17: 16 steps x 32 MFMA = 512 MFMA/wave;
//   per the measured per-wave law (~123-155 cy/serial MFMA, waves
//   multiplex the pipe: R14), wall ~= one wave's chain ~= 26-34us.
//   Folds: fwd and bwd chains interleave in the SAME 8 barrier rounds
//   (round f: wave f folds fwd, wave 8+(7-f) folds bwd). u,w,Sseg all
//   in-block -> combine fully fused (dot in wave 0, gold in wave 1,
//   R12-verified pattern). No ws, no second kernel.

#define TAGS 50
#define LEN 256
#define NB 256
#define TOTF (NB * LEN * TAGS)
#define INV_LN2 1.4426950408889634f
#define LN2 0.6931471805599453f

typedef __attribute__((ext_vector_type(8))) short bf16x8;
typedef __attribute__((ext_vector_type(4))) float f32x4;
typedef __attribute__((ext_vector_type(4), aligned(4))) float f32x4u;

#if __has_builtin(__builtin_amdgcn_exp2f)
#define EXP2F(x) __builtin_amdgcn_exp2f(x)
#else
#define EXP2F(x) exp2f(x)
#endif
#if __has_builtin(__builtin_amdgcn_logf)
#define LOG2F(x) __builtin_amdgcn_logf(x)
#else
#define LOG2F(x) log2f(x)
#endif
#if __has_builtin(__builtin_amdgcn_rcpf)
#define RCPF(x) __builtin_amdgcn_rcpf(x)
#else
#define RCPF(x) (1.0f / (x))
#endif

__device__ __forceinline__ float readlane_f(float v, int srclane) {
  return __builtin_bit_cast(float,
      __builtin_amdgcn_readlane(__builtin_bit_cast(int, v), srclane));
}

__device__ __forceinline__ int bf16pairInit(float lo, float hi) {
  unsigned lb = (__builtin_bit_cast(unsigned, lo) + 0x8000u) >> 16;
  unsigned hb = (__builtin_bit_cast(unsigned, hi) + 0x8000u) & 0xFFFF0000u;
  return (int)(hb | lb);
}

// One-instruction pack: dst = (bf16(hi)<<16) | bf16(lo), RNE.
#define PACK2(dst, lo, hi) \
  asm("v_cvt_pk_bf16_f32 %0, %1, %2" : "=v"(dst) : "v"(lo), "v"(hi))

union U8 { int i[4]; bf16x8 v; };

__global__ __launch_bounds__(1024, 1) void crf_fused_kernel(
    const float* __restrict__ feats,   // (B, L, T)
    const float* __restrict__ trans,   // (T, T)
    const int*   __restrict__ tags,    // (B, L)
    const int*   __restrict__ mask,    // (B, L)
    float*       __restrict__ out)     // (B,)
{
  const int b    = blockIdx.x;
  const int tid  = threadIdx.x;
  const int w    = tid >> 6;
  const int lane = tid & 63;
  const int q    = lane >> 4;
  const int n    = lane & 15;
  const bool isf = (w < 8);
  const int  sw  = isf ? w : w - 8;   // segment index within direction

  __shared__ __align__(16) float xf_lds[64];
  __shared__ __align__(16) float xb_lds[64];
  __shared__ float Sseg[16];
  __shared__ float norm_s, gold_s;

  // ---- mask ballots (wave-uniform SGPRs; identical in every wave) ----
  const int* mbp = mask + b * LEN;
  const unsigned long long mb0 = __ballot(mbp[lane] > 0);
  const unsigned long long mb1 = __ballot(mbp[64 + lane] > 0);
  const unsigned long long mb2 = __ballot(mbp[128 + lane] > 0);
  const unsigned long long mb3 = __ballot(mbp[192 + lane] > 0);
#define MASKBIT(L)                                                          \
  ((int)(((((L) & 128) ? (((L) & 64) ? mb3 : mb2)                           \
                       : (((L) & 64) ? mb1 : mb0)) >> ((L) & 63)) & 1ull))

  // ---- Constant A-frags: fwd waves = E2^T orientation, bwd = E2 rows ----
  U8 Afr[4][2];
#pragma unroll
  for (int t = 0; t < 4; ++t)
#pragma unroll
    for (int c = 0; c < 2; ++c)
#pragma unroll
      for (int r = 0; r < 4; ++r) {
        const int col = 16 * t + n;
        const int tag0 = 16 * c + 4 * q + r;
        const int tag1 = tag0 + 32;
        float e0 = 0.0f, e1 = 0.0f;
        if (col < TAGS) {
          if (tag0 < TAGS)
            e0 = EXP2F((isf ? trans[tag0 * TAGS + col]
                            : trans[col * TAGS + tag0]) * INV_LN2);
          if (tag1 < TAGS)
            e1 = EXP2F((isf ? trans[tag1 * TAGS + col]
                            : trans[col * TAGS + tag1]) * INV_LN2);
        }
        Afr[t][c].i[r] = bf16pairInit(e0, e1);
      }

  const f32x4 zero4 = {0.0f, 0.0f, 0.0f, 0.0f};

  // State init P = I (identical expression for both layouts).
  f32x4 d[4][4];
#pragma unroll
  for (int J = 0; J < 4; ++J)
#pragma unroll
    for (int I = 0; I < 4; ++I)
#pragma unroll
      for (int r = 0; r < 4; ++r)
        d[J][I][r] = (16 * J + n == 16 * I + 4 * q + r) ? 1.0f : 0.0f;

  float S = 0.0f;
  f32x4u rA[4], rB[4];

#define LOADG(BK, L) do {                                                   \
    const float* _p = feats + (size_t)b * (LEN * TAGS) + (size_t)(L) * TAGS;\
    BK[0] = *(const f32x4u*)(_p + 4 * q);                                   \
    BK[1] = *(const f32x4u*)(_p + 16 + 4 * q);                              \
    BK[2] = *(const f32x4u*)(_p + 32 + 4 * q);                              \
    const float* _p3 = _p + 46 + 4 * q;                                     \
    const float* _lim = feats + (TOTF - 4);                                 \
    if (_p3 > _lim) _p3 = _lim;                                             \
    BK[3] = *(const f32x4u*)_p3;                                            \
  } while (0)

#define RENORMM() do {                                                      \
    const float _cc = readlane_f(d[0][0][0], 0);                            \
    const float _rr = RCPF(_cc);                                            \
    S += LOG2F(_cc);                                                        \
    _Pragma("unroll") for (int _J = 0; _J < 4; ++_J)                        \
    _Pragma("unroll") for (int _I = 0; _I < 4; ++_I)                        \
    _Pragma("unroll") for (int _r = 0; _r < 4; ++_r)                        \
      d[_J][_I][_r] *= _rr;                                                 \
  } while (0)

  // ev from raw EH (R14's I=3 trick: only q=0,r<2 matter; junk lands on
  // structurally-zero rows/cols).
#define MKEV(EH)                                                            \
    float ev[4][4];                                                         \
    _Pragma("unroll") for (int _i = 0; _i < 3; ++_i)                        \
    _Pragma("unroll") for (int _r = 0; _r < 4; ++_r)                        \
      ev[_i][_r] = EXP2F(EH[_i][_r] * INV_LN2);                             \
    ev[3][0] = EXP2F(EH[3][2] * INV_LN2);                                   \
    ev[3][1] = EXP2F(EH[3][3] * INV_LN2);                                   \
    ev[3][2] = 0.0f; ev[3][3] = 0.0f

#define MFMA8J(B0_, B1_)                                                    \
    f32x4 t0 = __builtin_amdgcn_mfma_f32_16x16x32_bf16(Afr[0][1].v, B1_.v, zero4, 0, 0, 0); \
    f32x4 t1 = __builtin_amdgcn_mfma_f32_16x16x32_bf16(Afr[1][1].v, B1_.v, zero4, 0, 0, 0); \
    f32x4 t2 = __builtin_amdgcn_mfma_f32_16x16x32_bf16(Afr[2][1].v, B1_.v, zero4, 0, 0, 0); \
    f32x4 t3 = __builtin_amdgcn_mfma_f32_16x16x32_bf16(Afr[3][1].v, B1_.v, zero4, 0, 0, 0); \
    t0 = __builtin_amdgcn_mfma_f32_16x16x32_bf16(Afr[0][0].v, B0_.v, t0, 0, 0, 0); \
    t1 = __builtin_amdgcn_mfma_f32_16x16x32_bf16(Afr[1][0].v, B0_.v, t1, 0, 0, 0); \
    t2 = __builtin_amdgcn_mfma_f32_16x16x32_bf16(Afr[2][0].v, B0_.v, t2, 0, 0, 0); \
    t3 = __builtin_amdgcn_mfma_f32_16x16x32_bf16(Afr[3][0].v, B0_.v, t3, 0, 0, 0)

  // fwd: P <- (P.E2) col-scaled (R14-verified + l<=127 gate).
#define STEPF(EH, L) do {                                                   \
    if ((L) <= 127 && MASKBIT(L)) {                                         \
      MKEV(EH);                                                             \
      _Pragma("unroll") for (int _J = 0; _J < 4; ++_J) {                    \
        U8 B0, B1;                                                          \
        _Pragma("unroll") for (int _r = 0; _r < 4; ++_r) {                  \
          PACK2(B0.i[_r], d[_J][0][_r], d[_J][2][_r]);                      \
          PACK2(B1.i[_r], d[_J][1][_r], d[_J][3][_r]);                      \
        }                                                                   \
        MFMA8J(B0, B1);                                                     \
        _Pragma("unroll") for (int _r = 0; _r < 4; ++_r) {                  \
          d[_J][0][_r] = t0[_r] * ev[0][_r];                                \
          d[_J][1][_r] = t1[_r] * ev[1][_r];                                \
          d[_J][2][_r] = t2[_r] * ev[2][_r];                                \
          d[_J][3][_r] = t3[_r] * ev[3][_r];                                \
        }                                                                   \
      }                                                                     \
    }                                                                       \
  } while (0)

  // bwd: Q <- E2.(diag(eh).Q): eh PRE-scales the B K-slots (rows of Q).
#define STEPB(EH, L) do {                                                   \
    if (MASKBIT(L)) {                                                       \
      MKEV(EH);                                                             \
      _Pragma("unroll") for (int _J = 0; _J < 4; ++_J) {                    \
        U8 B0, B1;                                                          \
        _Pragma("unroll") for (int _r = 0; _r < 4; ++_r) {                  \
          PACK2(B0.i[_r], ev[0][_r] * d[_J][0][_r], ev[2][_r] * d[_J][2][_r]); \
          PACK2(B1.i[_r], ev[1][_r] * d[_J][1][_r], ev[3][_r] * d[_J][3][_r]); \
        }                                                                   \
        MFMA8J(B0, B1);                                                     \
        _Pragma("unroll") for (int _r = 0; _r < 4; ++_r) {                  \
          d[_J][0][_r] = t0[_r];                                            \
          d[_J][1][_r] = t1[_r];                                            \
          d[_J][2][_r] = t2[_r];                                            \
          d[_J][3][_r] = t3[_r];                                            \
        }                                                                   \
      }                                                                     \
    }                                                                       \
  } while (0)

  // ---- Segment scan: 16 steps/wave (fwd wave7's l=128 step gated off) ----
  if (isf) {
    int l = 1 + 16 * sw;
    LOADG(rA, l);
    LOADG(rB, l + 1);
    for (int kk = 0; kk < 8; ++kk) {
      if ((kk & 1) == 0) RENORMM();
      STEPF(rA, l); LOADG(rA, l + 2);
      ++l;
      STEPF(rB, l); LOADG(rB, l + 2);
      ++l;
    }
  } else {
    int l = 143 + 16 * sw;
    LOADG(rA, l);
    LOADG(rB, l - 1);
    for (int kk = 0; kk < 8; ++kk) {
      if ((kk & 1) == 0) RENORMM();
      STEPB(rA, l); LOADG(rA, l - 2);
      --l;
      STEPB(rB, l); LOADG(rB, l - 2);
      --l;
    }
  }

  __syncthreads();

  // ---- Folds: fwd chain (waves 0->7) and bwd chain (waves 15->8)
  //      interleaved in the same 8 barrier rounds; P stays in regs. ----
  for (int f = 0; f < 8; ++f) {
    if (w == f) {
      // fwd: y = x . P (contract P's row 16J+n, reduce over n)
      float xv[4];
      if (f == 0) {
#pragma unroll
        for (int J = 0; J < 4; ++J) {
          const int tg = 16 * J + n;
          xv[J] = (tg < TAGS)
                      ? EXP2F(feats[(size_t)b * (LEN * TAGS) + tg] * INV_LN2)
                      : 0.0f;
        }
      } else {
#pragma unroll
        for (int J = 0; J < 4; ++J) xv[J] = xf_lds[16 * J + n];
      }
      float p[4][4];
#pragma unroll
      for (int I = 0; I < 4; ++I)
#pragma unroll
        for (int r = 0; r < 4; ++r)
          p[I][r] = xv[0] * d[0][I][r] + xv[1] * d[1][I][r] +
                    xv[2] * d[2][I][r] + xv[3] * d[3][I][r];
#pragma unroll
      for (int off = 1; off <= 8; off <<= 1)
#pragma unroll
        for (int I = 0; I < 4; ++I)
#pragma unroll
          for (int r = 0; r < 4; ++r)
            p[I][r] += __shfl_xor(p[I][r], off, 64);
      const float cc = readlane_f(p[0][0], 0);
      const float rr = RCPF(cc);
      S += LOG2F(cc);
      if (n == 0) {
#pragma unroll
        for (int I = 0; I < 4; ++I)
#pragma unroll
          for (int r = 0; r < 4; ++r)
            xf_lds[16 * I + 4 * q + r] = p[I][r] * rr;
      }
      if (lane == 0) Sseg[w] = S;
    }
    if (w == 8 + (7 - f)) {
      // bwd: x' = Q . x (contract Q's col 16J+n, reduce over n)
      float xv[4];
      if (f == 0) {
#pragma unroll
        for (int J = 0; J < 4; ++J) xv[J] = (16 * J + n < TAGS) ? 1.0f : 0.0f;
      } else {
#pragma unroll
        for (int J = 0; J < 4; ++J) xv[J] = xb_lds[16 * J + n];
      }
      float t[4][4];
#pragma unroll
      for (int I = 0; I < 4; ++I)
#pragma unroll
        for (int r = 0; r < 4; ++r)
          t[I][r] = xv[0] * d[0][I][r] + xv[1] * d[1][I][r] +
                    xv[2] * d[2][I][r] + xv[3] * d[3][I][r];
#pragma unroll
      for (int off = 1; off <= 8; off <<= 1)
#pragma unroll
        for (int I = 0; I < 4; ++I)
#pragma unroll
          for (int r = 0; r < 4; ++r)
            t[I][r] += __shfl_xor(t[I][r], off, 64);
      const float cc = readlane_f(t[0][0], 0);
      const float rr = RCPF(cc);
      S += LOG2F(cc);
      if (n == 0) {
#pragma unroll
        for (int I = 0; I < 4; ++I)
#pragma unroll
          for (int r = 0; r < 4; ++r)
            xb_lds[16 * I + 4 * q + r] = t[I][r] * rr;
      }
      if (lane == 0) Sseg[w] = S;
    }
    __syncthreads();
  }

  // ---- Fused combine: dot in wave 0, gold in wave 1 (R12 pattern) ----
  if (w == 0) {
    float s = xf_lds[lane] * xb_lds[lane];
#pragma unroll
    for (int off = 32; off; off >>= 1) s += __shfl_xor(s, off, 64);
    if (lane == 0) {
      float Ssum = 0.0f;
#pragma unroll
      for (int i = 0; i < 16; ++i) Ssum += Sseg[i];
      norm_s = LN2 * (Ssum + LOG2F(s));
    }
  } else if (w == 1) {
    const float* fb = feats + (size_t)b * (LEN * TAGS);
    const int* tb = tags + b * LEN;
    float gp = 0.0f;
#pragma unroll
    for (int k = 0; k < 4; ++k) {
      const int p = lane + 64 * k;
      const int tg = tb[p];
      if (mbp[p] > 0) {
        float vv = fb[p * TAGS + tg];
        if (p >= 1) vv += trans[tb[p - 1] * TAGS + tg];
        gp += vv;
      }
    }
#pragma unroll
    for (int off = 32; off; off >>= 1) gp += __shfl_xor(gp, off, 64);
    if (lane == 0) gold_s = gp;
  }

  __syncthreads();
  if (tid == 0) out[b] = norm_s - gold_s;

#undef MASKBIT
#undef LOADG
#undef RENORMM
#undef MKEV
#undef MFMA8J
#undef STEPF
#undef STEPB
}

extern "C" void kernel_launch(void* const* d_in, const int* in_sizes, int n_in,
                              void* d_out, int out_size, void* d_ws, size_t ws_size,
                              hipStream_t stream) {
  const float* feats = (const float*)d_in[0];
  const float* trans = (const float*)d_in[1];
  const int*   tags  = (const int*)d_in[2];
  const int*   mask  = (const int*)d_in[3];
  float* out = (float*)d_out;
  (void)d_ws; (void)ws_size;

  crf_fused_kernel<<<NB, 1024, 0, stream>>>(feats, trans, tags, mask, out);
}

// Round 9
// 168.671 us; speedup vs baseline: 1.6961x; 1.6961x over previous
//
#include <hip/hip_runtime.h>
#include <math.h>

// CRF loss: B=256, L=256, T=50.
// R19: R18 (fused 1024-thr block, 16 waves: 8 fwd + 8 bwd segments) slimmed
//   to fit the 128-reg/wave cap that 4 waves/SIMD imposes. R18 spilled
//   (VGPR 64 + 270MB FETCH / 390MB WRITE scratch, 230us) because
//   d(64)+Afr(16)+rA/rB(32)+ev(16)+temps > 128. R19 deletes rA/rB and ev:
//   - exp2(emissions) staged ONCE in LDS flexp[256][52] (53KB, R13-proven
//     magic-/50 scatter; cols 50,51 = 0; 64-float guard). Junk reads past
//     col 49 are finite and multiply structurally-zero state (R16-verified
//     argument), so no special-casing needed.
//   - per-step eh = 4 broadcast ds_read_b128 (16B-aligned: 52*4=13*16;
//     2-way bank aliasing is free). fwd reads at step start, consumes at
//     step end (covered); bwd just-in-time (~120cy/step, ~0.8us total).
//   Register plan: d 64 + Afr 16 + eh 16 + temps ~ 110 < 128.
// Occupancy model (R14/R17/R18 counters): real footprint was in the
//   2-waves/SIMD class -> 512-block grids ran as 2 sequential rounds
//   (R17: 69us = 2x(26+8)). One 1024-thr block/CU = single round.
// All algebra is R16/R18-verified and unchanged: STEPF right-mult,
// STEPB left-mult, mask ballots, renorm/4, interleaved folds, fused
// combine (dot wave 0, gold wave 1).

#define TAGS 50
#define LEN 256
#define NB 256
#define RS 52
#define FLN (LEN * RS + 64)
#define INV_LN2 1.4426950408889634f
#define LN2 0.6931471805599453f

typedef __attribute__((ext_vector_type(8))) short bf16x8;
typedef __attribute__((ext_vector_type(4))) float f32x4;

#if __has_builtin(__builtin_amdgcn_exp2f)
#define EXP2F(x) __builtin_amdgcn_exp2f(x)
#else
#define EXP2F(x) exp2f(x)
#endif
#if __has_builtin(__builtin_amdgcn_logf)
#define LOG2F(x) __builtin_amdgcn_logf(x)
#else
#define LOG2F(x) log2f(x)
#endif
#if __has_builtin(__builtin_amdgcn_rcpf)
#define RCPF(x) __builtin_amdgcn_rcpf(x)
#else
#define RCPF(x) (1.0f / (x))
#endif

__device__ __forceinline__ float readlane_f(float v, int srclane) {
  return __builtin_bit_cast(float,
      __builtin_amdgcn_readlane(__builtin_bit_cast(int, v), srclane));
}

__device__ __forceinline__ int bf16pairInit(float lo, float hi) {
  unsigned lb = (__builtin_bit_cast(unsigned, lo) + 0x8000u) >> 16;
  unsigned hb = (__builtin_bit_cast(unsigned, hi) + 0x8000u) & 0xFFFF0000u;
  return (int)(hb | lb);
}

// One-instruction pack: dst = (bf16(hi)<<16) | bf16(lo), RNE.
#define PACK2(dst, lo, hi) \
  asm("v_cvt_pk_bf16_f32 %0, %1, %2" : "=v"(dst) : "v"(lo), "v"(hi))

union U8 { int i[4]; bf16x8 v; };

__global__ __launch_bounds__(1024, 1) void crf_fused_kernel(
    const float* __restrict__ feats,   // (B, L, T)
    const float* __restrict__ trans,   // (T, T)
    const int*   __restrict__ tags,    // (B, L)
    const int*   __restrict__ mask,    // (B, L)
    float*       __restrict__ out)     // (B,)
{
  const int b    = blockIdx.x;
  const int tid  = threadIdx.x;
  const int w    = tid >> 6;
  const int lane = tid & 63;
  const int q    = lane >> 4;
  const int n    = lane & 15;
  const bool isf = (w < 8);
  const int  sw  = isf ? w : w - 8;   // segment index within direction

  __shared__ __align__(16) float flexp[FLN];   // exp2(feat/ln2), pads 0
  __shared__ __align__(16) float xf_lds[64];
  __shared__ __align__(16) float xb_lds[64];
  __shared__ float Sseg[16];
  __shared__ float norm_s, gold_s;

  // ---- Preload: feats -> exp2 LDS table (R13-proven magic /50 scatter) ----
  {
    const float4* fv = (const float4*)(feats + (size_t)b * (LEN * TAGS));
    for (int i4 = tid; i4 < (LEN * TAGS) / 4; i4 += 1024) {
      float4 v4 = fv[i4];
      float vv[4] = {v4.x, v4.y, v4.z, v4.w};
      const int base = i4 * 4;
#pragma unroll
      for (int e = 0; e < 4; ++e) {
        const int idx = base + e;
        const unsigned row =
            (unsigned)(((unsigned long long)(unsigned)idx * 1374389535ull) >> 36);
        const int col = idx - (int)row * 50;
        flexp[row * RS + col] = EXP2F(vv[e] * INV_LN2);
      }
    }
    for (int i = tid; i < LEN; i += 1024) {
      flexp[i * RS + 50] = 0.0f;
      flexp[i * RS + 51] = 0.0f;
    }
    if (tid < 64) flexp[LEN * RS + tid] = 0.0f;
  }

  // ---- mask ballots (wave-uniform SGPRs; identical in every wave) ----
  const int* mbp = mask + b * LEN;
  const unsigned long long mb0 = __ballot(mbp[lane] > 0);
  const unsigned long long mb1 = __ballot(mbp[64 + lane] > 0);
  const unsigned long long mb2 = __ballot(mbp[128 + lane] > 0);
  const unsigned long long mb3 = __ballot(mbp[192 + lane] > 0);
#define MASKBIT(L)                                                          \
  ((int)(((((L) & 128) ? (((L) & 64) ? mb3 : mb2)                           \
                       : (((L) & 64) ? mb1 : mb0)) >> ((L) & 63)) & 1ull))

  // ---- Constant A-frags: fwd waves = E2^T orientation, bwd = E2 rows ----
  U8 Afr[4][2];
#pragma unroll
  for (int t = 0; t < 4; ++t)
#pragma unroll
    for (int c = 0; c < 2; ++c)
#pragma unroll
      for (int r = 0; r < 4; ++r) {
        const int col = 16 * t + n;
        const int tag0 = 16 * c + 4 * q + r;
        const int tag1 = tag0 + 32;
        float e0 = 0.0f, e1 = 0.0f;
        if (col < TAGS) {
          if (tag0 < TAGS)
            e0 = EXP2F((isf ? trans[tag0 * TAGS + col]
                            : trans[col * TAGS + tag0]) * INV_LN2);
          if (tag1 < TAGS)
            e1 = EXP2F((isf ? trans[tag1 * TAGS + col]
                            : trans[col * TAGS + tag1]) * INV_LN2);
        }
        Afr[t][c].i[r] = bf16pairInit(e0, e1);
      }

  const f32x4 zero4 = {0.0f, 0.0f, 0.0f, 0.0f};

  // State init P = I (identical expression for both layouts).
  f32x4 d[4][4];
#pragma unroll
  for (int J = 0; J < 4; ++J)
#pragma unroll
    for (int I = 0; I < 4; ++I)
#pragma unroll
      for (int r = 0; r < 4; ++r)
        d[J][I][r] = (16 * J + n == 16 * I + 4 * q + r) ? 1.0f : 0.0f;

  float S = 0.0f;

  __syncthreads();   // flexp ready

#define RENORMM() do {                                                      \
    const float _cc = readlane_f(d[0][0][0], 0);                            \
    const float _rr = RCPF(_cc);                                            \
    S += LOG2F(_cc);                                                        \
    _Pragma("unroll") for (int _J = 0; _J < 4; ++_J)                        \
    _Pragma("unroll") for (int _I = 0; _I < 4; ++_I)                        \
    _Pragma("unroll") for (int _r = 0; _r < 4; ++_r)                        \
      d[_J][_I][_r] *= _rr;                                                 \
  } while (0)

  // per-step eh: 4 broadcast ds_read_b128 (row L, col block 16I+4q).
#define LDEH(E0, E1, E2_, E3_, L) do {                                      \
    const float* _p = &flexp[(L) * RS + 4 * q];                             \
    E0 = *(const f32x4*)(_p);                                               \
    E1 = *(const f32x4*)(_p + 16);                                          \
    E2_ = *(const f32x4*)(_p + 32);                                         \
    E3_ = *(const f32x4*)(_p + 48);                                         \
  } while (0)

#define MFMA8J(B0_, B1_)                                                    \
    f32x4 t0 = __builtin_amdgcn_mfma_f32_16x16x32_bf16(Afr[0][1].v, B1_.v, zero4, 0, 0, 0); \
    f32x4 t1 = __builtin_amdgcn_mfma_f32_16x16x32_bf16(Afr[1][1].v, B1_.v, zero4, 0, 0, 0); \
    f32x4 t2 = __builtin_amdgcn_mfma_f32_16x16x32_bf16(Afr[2][1].v, B1_.v, zero4, 0, 0, 0); \
    f32x4 t3 = __builtin_amdgcn_mfma_f32_16x16x32_bf16(Afr[3][1].v, B1_.v, zero4, 0, 0, 0); \
    t0 = __builtin_amdgcn_mfma_f32_16x16x32_bf16(Afr[0][0].v, B0_.v, t0, 0, 0, 0); \
    t1 = __builtin_amdgcn_mfma_f32_16x16x32_bf16(Afr[1][0].v, B0_.v, t1, 0, 0, 0); \
    t2 = __builtin_amdgcn_mfma_f32_16x16x32_bf16(Afr[2][0].v, B0_.v, t2, 0, 0, 0); \
    t3 = __builtin_amdgcn_mfma_f32_16x16x32_bf16(Afr[3][0].v, B0_.v, t3, 0, 0, 0)

  // fwd: P <- (P.E2) col-scaled by eh (eh read early, used late: covered).
#define STEPF(L) do {                                                       \
    if ((L) <= 127 && MASKBIT(L)) {                                         \
      f32x4 e0, e1, e2, e3;                                                 \
      LDEH(e0, e1, e2, e3, L);                                              \
      _Pragma("unroll") for (int _J = 0; _J < 4; ++_J) {                    \
        U8 B0, B1;                                                          \
        _Pragma("unroll") for (int _r = 0; _r < 4; ++_r) {                  \
          PACK2(B0.i[_r], d[_J][0][_r], d[_J][2][_r]);                      \
          PACK2(B1.i[_r], d[_J][1][_r], d[_J][3][_r]);                      \
        }                                                                   \
        MFMA8J(B0, B1);                                                     \
        _Pragma("unroll") for (int _r = 0; _r < 4; ++_r) {                  \
          d[_J][0][_r] = t0[_r] * e0[_r];                                   \
          d[_J][1][_r] = t1[_r] * e1[_r];                                   \
          d[_J][2][_r] = t2[_r] * e2[_r];                                   \
          d[_J][3][_r] = t3[_r] * e3[_r];                                   \
        }                                                                   \
      }                                                                     \
    }                                                                       \
  } while (0)

  // bwd: Q <- E2.(diag(eh).Q): eh PRE-scales the B K-slots (just-in-time).
#define STEPB(L) do {                                                       \
    if (MASKBIT(L)) {                                                       \
      f32x4 e0, e1, e2, e3;                                                 \
      LDEH(e0, e1, e2, e3, L);                                              \
      _Pragma("unroll") for (int _J = 0; _J < 4; ++_J) {                    \
        U8 B0, B1;                                                          \
        _Pragma("unroll") for (int _r = 0; _r < 4; ++_r) {                  \
          PACK2(B0.i[_r], e0[_r] * d[_J][0][_r], e2[_r] * d[_J][2][_r]);    \
          PACK2(B1.i[_r], e1[_r] * d[_J][1][_r], e3[_r] * d[_J][3][_r]);    \
        }                                                                   \
        MFMA8J(B0, B1);                                                     \
        _Pragma("unroll") for (int _r = 0; _r < 4; ++_r) {                  \
          d[_J][0][_r] = t0[_r];                                            \
          d[_J][1][_r] = t1[_r];                                            \
          d[_J][2][_r] = t2[_r];                                            \
          d[_J][3][_r] = t3[_r];                                            \
        }                                                                   \
      }                                                                     \
    }                                                                       \
  } while (0)

  // ---- Segment scan: 16 steps/wave (fwd wave7's l=128 step gated off) ----
  if (isf) {
    int l = 1 + 16 * sw;
    for (int kk = 0; kk < 16; ++kk) {
      if ((kk & 3) == 0) RENORMM();
      STEPF(l);
      ++l;
    }
  } else {
    int l = 143 + 16 * sw;
    for (int kk = 0; kk < 16; ++kk) {
      if ((kk & 3) == 0) RENORMM();
      STEPB(l);
      --l;
    }
  }

  __syncthreads();

  // ---- Folds: fwd chain (waves 0->7) and bwd chain (waves 15->8)
  //      interleaved in the same 8 barrier rounds; P stays in regs. ----
  for (int f = 0; f < 8; ++f) {
    if (w == f) {
      // fwd: y = x . P (contract P's row 16J+n, reduce over n)
      float xv[4];
      if (f == 0) {
#pragma unroll
        for (int J = 0; J < 4; ++J) {
          const int tg = 16 * J + n;
          xv[J] = (tg < TAGS) ? flexp[tg] : 0.0f;   // row 0, already exp2'd
        }
      } else {
#pragma unroll
        for (int J = 0; J < 4; ++J) xv[J] = xf_lds[16 * J + n];
      }
      float p[4][4];
#pragma unroll
      for (int I = 0; I < 4; ++I)
#pragma unroll
        for (int r = 0; r < 4; ++r)
          p[I][r] = xv[0] * d[0][I][r] + xv[1] * d[1][I][r] +
                    xv[2] * d[2][I][r] + xv[3] * d[3][I][r];
#pragma unroll
      for (int off = 1; off <= 8; off <<= 1)
#pragma unroll
        for (int I = 0; I < 4; ++I)
#pragma unroll
          for (int r = 0; r < 4; ++r)
            p[I][r] += __shfl_xor(p[I][r], off, 64);
      const float cc = readlane_f(p[0][0], 0);
      const float rr = RCPF(cc);
      S += LOG2F(cc);
      if (n == 0) {
#pragma unroll
        for (int I = 0; I < 4; ++I)
#pragma unroll
          for (int r = 0; r < 4; ++r)
            xf_lds[16 * I + 4 * q + r] = p[I][r] * rr;
      }
      if (lane == 0) Sseg[w] = S;
    }
    if (w == 8 + (7 - f)) {
      // bwd: x' = Q . x (contract Q's col 16J+n, reduce over n)
      float xv[4];
      if (f == 0) {
#pragma unroll
        for (int J = 0; J < 4; ++J) xv[J] = (16 * J + n < TAGS) ? 1.0f : 0.0f;
      } else {
#pragma unroll
        for (int J = 0; J < 4; ++J) xv[J] = xb_lds[16 * J + n];
      }
      float t[4][4];
#pragma unroll
      for (int I = 0; I < 4; ++I)
#pragma unroll
        for (int r = 0; r < 4; ++r)
          t[I][r] = xv[0] * d[0][I][r] + xv[1] * d[1][I][r] +
                    xv[2] * d[2][I][r] + xv[3] * d[3][I][r];
#pragma unroll
      for (int off = 1; off <= 8; off <<= 1)
#pragma unroll
        for (int I = 0; I < 4; ++I)
#pragma unroll
          for (int r = 0; r < 4; ++r)
            t[I][r] += __shfl_xor(t[I][r], off, 64);
      const float cc = readlane_f(t[0][0], 0);
      const float rr = RCPF(cc);
      S += LOG2F(cc);
      if (n == 0) {
#pragma unroll
        for (int I = 0; I < 4; ++I)
#pragma unroll
          for (int r = 0; r < 4; ++r)
            xb_lds[16 * I + 4 * q + r] = t[I][r] * rr;
      }
      if (lane == 0) Sseg[w] = S;
    }
    __syncthreads();
  }

  // ---- Fused combine: dot in wave 0, gold in wave 1 (R12/R18 pattern) ----
  if (w == 0) {
    float s = xf_lds[lane] * xb_lds[lane];
#pragma unroll
    for (int off = 32; off; off >>= 1) s += __shfl_xor(s, off, 64);
    if (lane == 0) {
      float Ssum = 0.0f;
#pragma unroll
      for (int i = 0; i < 16; ++i) Ssum += Sseg[i];
      norm_s = LN2 * (Ssum + LOG2F(s));
    }
  } else if (w == 1) {
    const float* fb = feats + (size_t)b * (LEN * TAGS);
    const int* tb = tags + b * LEN;
    float gp = 0.0f;
#pragma unroll
    for (int k = 0; k < 4; ++k) {
      const int p = lane + 64 * k;
      const int tg = tb[p];
      if (mbp[p] > 0) {
        float vv = fb[p * TAGS + tg];
        if (p >= 1) vv += trans[tb[p - 1] * TAGS + tg];
        gp += vv;
      }
    }
#pragma unroll
    for (int off = 32; off; off >>= 1) gp += __shfl_xor(gp, off, 64);
    if (lane == 0) gold_s = gp;
  }

  __syncthreads();
  if (tid == 0) out[b] = norm_s - gold_s;

#undef MASKBIT
#undef RENORMM
#undef LDEH
#undef MFMA8J
#undef STEPF
#undef STEPB
}

extern "C" void kernel_launch(void* const* d_in, const int* in_sizes, int n_in,
                              void* d_out, int out_size, void* d_ws, size_t ws_size,
                              hipStream_t stream) {
  const float* feats = (const float*)d_in[0];
  const float* trans = (const float*)d_in[1];
  const int*   tags  = (const int*)d_in[2];
  const int*   mask  = (const int*)d_in[3];
  float* out = (float*)d_out;
  (void)d_ws; (void)ws_size;

  crf_fused_kernel<<<NB, 1024, 0, stream>>>(feats, trans, tags, mask, out);
}